// Round 2
// baseline (23.636 us; speedup 1.0000x reference)
//
#include <hip/hip_runtime.h>

// PowerDense: y[b,o] = sigmoid( sum_k x[b,k]^w[k,o] + bias[o] ),  B=8192, K=O=128.
// x^w = exp2(w * log2(x)); trans-pipe bound: 134M v_exp_f32 -> ~7us floor.
//
// Structure (R2): lane = row, columns uniform per wave.
//  - w[k][c0..c7] is wave-uniform -> scalar loads (s_load) via constant cache:
//    NO vector-memory traffic in the k-loop.
//  - log2(x) staged once per 64-row block in LDS as lx[64][129] (pad 129 =>
//    bank (lane+k)%32: conflict-free ds_read_b32 in the k-loop).
//  - 512 blocks x 256 thr = 2048 waves = 2/SIMD; LDS 33KB -> 2 blocks/CU.

#define B_DIM 8192
#define K_DIM 128
#define O_DIM 128
#define ROWS  64          // rows per block (= lanes per wave)
#define PAD   129         // lx row stride in floats (odd -> conflict-free)

__global__ __launch_bounds__(256) void powerdense_kernel(
    const float* __restrict__ x,      // [B, K]
    const float* __restrict__ w,      // [K, O]
    const float* __restrict__ bias,   // [O]
    float* __restrict__ out)          // [B, O]
{
    __shared__ float lx[ROWS * PAD];  // 33 KB

    const int tid  = threadIdx.x;
    const int row0 = blockIdx.x * ROWS;

    // ---- stage log2(x) for 64 rows: coalesced float4 reads, 8 passes ----
    #pragma unroll
    for (int p = 0; p < 8; ++p) {
        const int i  = p * 256 + tid;        // float4 index in the 64x128 tile
        const int r  = i >> 5;               // 0..63
        const int k4 = (i & 31) * 4;         // 0,4,...,124
        const float4 xv = *reinterpret_cast<const float4*>(
            &x[(size_t)(row0 + r) * K_DIM + k4]);
        float* d = &lx[r * PAD + k4];
        d[0] = __builtin_amdgcn_logf(xv.x);  // v_log_f32 = log2
        d[1] = __builtin_amdgcn_logf(xv.y);
        d[2] = __builtin_amdgcn_logf(xv.z);
        d[3] = __builtin_amdgcn_logf(xv.w);
    }
    __syncthreads();

    // ---- main loop: wave-uniform w (scalar pipe), lane-varying l (LDS) ----
    const int wave = tid >> 6;               // 0..3
    const int lane = tid & 63;               // = row offset
    const int row  = row0 + lane;
    // column base: uniform per wave; readfirstlane pins it to an SGPR so the
    // w-loads below are provably uniform -> s_load_dwordx4.
    const int c0 = __builtin_amdgcn_readfirstlane(blockIdx.y * 32 + wave * 8);

    float acc[8] = {0.f, 0.f, 0.f, 0.f, 0.f, 0.f, 0.f, 0.f};
    const float* __restrict__ lrow = &lx[lane * PAD];

    #pragma unroll 4
    for (int k = 0; k < K_DIM; ++k) {
        const float l = lrow[k];                       // ds_read_b32, conflict-free
        const float* wr = &w[(size_t)k * O_DIM + c0];  // uniform address
        const float4 w0 = *reinterpret_cast<const float4*>(wr);      // s_load
        const float4 w1 = *reinterpret_cast<const float4*>(wr + 4);  // s_load
        acc[0] += __builtin_amdgcn_exp2f(w0.x * l);
        acc[1] += __builtin_amdgcn_exp2f(w0.y * l);
        acc[2] += __builtin_amdgcn_exp2f(w0.z * l);
        acc[3] += __builtin_amdgcn_exp2f(w0.w * l);
        acc[4] += __builtin_amdgcn_exp2f(w1.x * l);
        acc[5] += __builtin_amdgcn_exp2f(w1.y * l);
        acc[6] += __builtin_amdgcn_exp2f(w1.z * l);
        acc[7] += __builtin_amdgcn_exp2f(w1.w * l);
    }

    // ---- epilogue: +bias, sigmoid, store 2x float4 ----
    const float4 b0 = *reinterpret_cast<const float4*>(&bias[c0]);
    const float4 b1 = *reinterpret_cast<const float4*>(&bias[c0 + 4]);
    const float LOG2E = 1.4426950408889634f;
    float y[8];
    y[0] = acc[0] + b0.x; y[1] = acc[1] + b0.y; y[2] = acc[2] + b0.z; y[3] = acc[3] + b0.w;
    y[4] = acc[4] + b1.x; y[5] = acc[5] + b1.y; y[6] = acc[6] + b1.z; y[7] = acc[7] + b1.w;
    float4 s0, s1;
    s0.x = 1.f / (1.f + __builtin_amdgcn_exp2f(-y[0] * LOG2E));
    s0.y = 1.f / (1.f + __builtin_amdgcn_exp2f(-y[1] * LOG2E));
    s0.z = 1.f / (1.f + __builtin_amdgcn_exp2f(-y[2] * LOG2E));
    s0.w = 1.f / (1.f + __builtin_amdgcn_exp2f(-y[3] * LOG2E));
    s1.x = 1.f / (1.f + __builtin_amdgcn_exp2f(-y[4] * LOG2E));
    s1.y = 1.f / (1.f + __builtin_amdgcn_exp2f(-y[5] * LOG2E));
    s1.z = 1.f / (1.f + __builtin_amdgcn_exp2f(-y[6] * LOG2E));
    s1.w = 1.f / (1.f + __builtin_amdgcn_exp2f(-y[7] * LOG2E));
    *reinterpret_cast<float4*>(&out[(size_t)row * O_DIM + c0])     = s0;
    *reinterpret_cast<float4*>(&out[(size_t)row * O_DIM + c0 + 4]) = s1;
}

extern "C" void kernel_launch(void* const* d_in, const int* in_sizes, int n_in,
                              void* d_out, int out_size, void* d_ws, size_t ws_size,
                              hipStream_t stream) {
    const float* x    = (const float*)d_in[0];  // [8192,128]
    const float* w    = (const float*)d_in[1];  // [128,128]
    const float* bias = (const float*)d_in[2];  // [128]
    float* out = (float*)d_out;                 // [8192,128]

    dim3 grid(B_DIM / ROWS, O_DIM / 32);        // 128 x 4 = 512 blocks
    dim3 block(256);
    powerdense_kernel<<<grid, block, 0, stream>>>(x, w, bias, out);
}